// Round 1
// baseline (410.159 us; speedup 1.0000x reference)
//
#include <hip/hip_runtime.h>
#include <stdint.h>

typedef int v4i  __attribute__((ext_vector_type(4)));
typedef int v16i __attribute__((ext_vector_type(16)));

#define M_TOK 8192
#define N_OUT 4096
#define K_IN  4096

#define BM 256
#define BN 256
#define BK 64                      // bytes (= i8 elems) per K-tile
#define NT (K_IN / BK)             // 64 K-tiles
#define RING_STRIDE 32768          // A 16 KiB + B 16 KiB per ring slot
#define LDS_BYTES (4 * RING_STRIDE)  // 128 KiB, ring of 4 (depth-2 prefetch)

// -------------------------------------------------------------------------
// Pack both int32-carrier tensors into int8 in one dispatch. (unchanged,
// BW-bound at ~38 us: 240 MB @ ~6.3 TB/s)
// -------------------------------------------------------------------------
__device__ __forceinline__ int pack4(int4 a) {
    return (a.x & 255) | ((a.y & 255) << 8) | ((a.z & 255) << 16) | ((a.w & 255) << 24);
}

__global__ __launch_bounds__(256) void pack_both(
    const int4* __restrict__ x, const int4* __restrict__ w,
    int* __restrict__ dA, int* __restrict__ dB, int n4x, int n4w)
{
    int i = blockIdx.x * blockDim.x + threadIdx.x;
    if (i < n4x) {
        dA[i] = pack4(x[i]);
    } else {
        int j = i - n4x;
        if (j < n4w) dB[j] = pack4(w[j]);
    }
}

// -------------------------------------------------------------------------
// i8 GEMM, 8-phase-class schedule (T2+T3+T4+T5 port of the 256^2 template):
//   256x256 tile, BK=64, 8 waves (2Mx4N), wave = 128x64 as 4x2 of
//   mfma_i32_32x32x32_i8 (128 acc VGPRs).
//   Ring-4 LDS (128 KiB dynamic), global_load_lds staging, counted
//   s_waitcnt vmcnt(8) once per K-tile (drain 8->4->0 in tail), raw
//   s_barrier pairs per phase, s_setprio(1) around MFMA clusters.
//   64-B rows: XOR swizzle f(r)=(r&3)^((r>>2)&1) on 16-B granules, applied
//   to the GLOBAL source (gload_lds dest is linear lane*16) and to the
//   ds_read granule -> every 8 rows cover all 32 banks (b128 at 8-cyc min).
// R1 history: 128^2 / BK=128 / 2x syncthreads (m97 structure) = ~360 us
// GEMM (~17% of 4404 TOPS i8 ceiling); barrier vmcnt(0) drain + doubled
// relative staging cost for i8 is the diagnosed bottleneck.
// -------------------------------------------------------------------------
__global__ __launch_bounds__(512, 2) void gemm_i8_kernel(
    const char* __restrict__ A8,      // [M][K] int8 row-major
    const char* __restrict__ B8,      // [N][K] int8 row-major
    const float* __restrict__ scale_ptr,
    float* __restrict__ out)          // [M][N] float + 1 scalar at end
{
    extern __shared__ char lds[];     // 4 ring slots: [A 16K | B 16K] each

    const int tid  = threadIdx.x;
    const int wave = tid >> 6;        // 0..7
    const int lane = tid & 63;

    // ---- bijective XCD swizzle of the 512-block grid (512 % 8 == 0).
    // Consecutive swizzled ids share bx (B panel) within an XCD.
    int wg = (blockIdx.x & 7) * 64 + (blockIdx.x >> 3);
    const int bx = wg >> 5;           // 0..15 (N tiles)
    const int by = wg & 31;           // 0..31 (M tiles)
    const int bm = by * BM;
    const int bn = bx * BN;

    const int wr = wave >> 2;         // 0..1
    const int wc = wave & 3;          // 0..3
    const int wm = wr * 128;          // wave row offset in tile
    const int wn = wc * 64;           // wave col offset in tile

    v16i acc[4][2];
#pragma unroll
    for (int mi = 0; mi < 4; ++mi)
#pragma unroll
        for (int nj = 0; nj < 2; ++nj)
#pragma unroll
            for (int r = 0; r < 16; ++r)
                acc[mi][nj][r] = 0;

    // ---- staging geometry: wave-load = 64 lanes x 16 B = 16 rows of 64 B.
    // Wave stages rows [wave*32, wave*32+32) of A and of B (2 loads each).
    // Source column granule pre-swizzled: g_src = (lane&3) ^ f(row),
    // f(row) = (row&3)^((row>>2)&1); row = base16 + (lane>>2) with base16
    // a multiple of 16, so f depends only on lane.
    const int srow = lane >> 2;                                   // 0..15
    const int sgr  = (lane & 3) ^ ((srow & 3) ^ ((srow >> 2) & 1));

    const char* gA[2]; const char* gB[2];
    int ldsAoff[2], ldsBoff[2];
#pragma unroll
    for (int q = 0; q < 2; ++q) {
        const int r0 = wave * 32 + q * 16;
        gA[q] = A8 + (size_t)(bm + r0 + srow) * K_IN + sgr * 16;
        gB[q] = B8 + (size_t)(bn + r0 + srow) * K_IN + sgr * 16;
        ldsAoff[q] = r0 * 64;              // A at slot offset 0
        ldsBoff[q] = 16384 + r0 * 64;      // B at slot offset 16 KiB
    }

#define ISSUE(tile, q) do {                                                  \
        char* _rb = lds + ((tile) & 3) * RING_STRIDE;                        \
        const int _k0 = (tile) * BK;                                         \
        __builtin_amdgcn_global_load_lds(                                    \
            (const __attribute__((address_space(1))) void*)(gA[q] + _k0),    \
            (__attribute__((address_space(3))) void*)(_rb + ldsAoff[q]),     \
            16, 0, 0);                                                       \
        __builtin_amdgcn_global_load_lds(                                    \
            (const __attribute__((address_space(1))) void*)(gB[q] + _k0),    \
            (__attribute__((address_space(3))) void*)(_rb + ldsBoff[q]),     \
            16, 0, 0);                                                       \
    } while (0)

    // ---- fragment geometry (32x32x32 i8): lane reads 16 B of row fm at
    // granule g = kk*2 + fh; stored LDS granule = g ^ f(row).
    const int fm  = lane & 31;
    const int fh  = lane >> 5;                       // 0/1
    const int fsw = (fm & 3) ^ ((fm >> 2) & 1);      // f(row) (row%32 == fm)
    const int g0  = ((0 + fh) ^ fsw) << 4;           // kk=0 byte offset
    const int g1  = ((2 + fh) ^ fsw) << 4;           // kk=1 byte offset
    const int abase = (wm + fm) * 64;                // + mi*2048
    const int bbase = 16384 + (wn + fm) * 64;        // + nj*2048

    // ---- prologue: tiles 0,1,2 in flight (12 issues/wave)
    ISSUE(0, 0); ISSUE(0, 1);
    ISSUE(1, 0); ISSUE(1, 1);
    ISSUE(2, 0); ISSUE(2, 1);
    asm volatile("s_waitcnt vmcnt(8)" ::: "memory");   // tile 0 landed
    __builtin_amdgcn_s_barrier();

    for (int t = 0; t < NT; ++t) {
        char* rb = lds + (t & 3) * RING_STRIDE;
        const bool pf = (t + 3 < NT);
        v4i af[4], bf[2];

        // ================= phase 0 (kk = 0) =================
#pragma unroll
        for (int mi = 0; mi < 4; ++mi)
            af[mi] = *(const v4i*)(rb + abase + mi * 2048 + g0);
#pragma unroll
        for (int nj = 0; nj < 2; ++nj)
            bf[nj] = *(const v4i*)(rb + bbase + nj * 2048 + g0);
        if (pf) ISSUE(t + 3, 0);           // 2 prefetch issues
        __builtin_amdgcn_s_barrier();
        __builtin_amdgcn_s_setprio(1);
#pragma unroll
        for (int mi = 0; mi < 4; ++mi)
#pragma unroll
            for (int nj = 0; nj < 2; ++nj)
                acc[mi][nj] = __builtin_amdgcn_mfma_i32_32x32x32_i8(
                    af[mi], bf[nj], acc[mi][nj], 0, 0, 0);
        __builtin_amdgcn_s_setprio(0);
        __builtin_amdgcn_s_barrier();

        // ================= phase 1 (kk = 1) =================
#pragma unroll
        for (int mi = 0; mi < 4; ++mi)
            af[mi] = *(const v4i*)(rb + abase + mi * 2048 + g1);
#pragma unroll
        for (int nj = 0; nj < 2; ++nj)
            bf[nj] = *(const v4i*)(rb + bbase + nj * 2048 + g1);
        if (pf) ISSUE(t + 3, 1);           // remaining 2 prefetch issues
        __builtin_amdgcn_s_barrier();
        __builtin_amdgcn_s_setprio(1);
#pragma unroll
        for (int mi = 0; mi < 4; ++mi)
#pragma unroll
            for (int nj = 0; nj < 2; ++nj)
                acc[mi][nj] = __builtin_amdgcn_mfma_i32_32x32x32_i8(
                    af[mi], bf[nj], acc[mi][nj], 0, 0, 0);
        __builtin_amdgcn_s_setprio(0);

        // counted wait: tile t+1 must be resident before next iteration's
        // ds_reads. Outstanding per wave: tile t+2 (4) + tile t+3 (4).
        const int rem = NT - 2 - t;        // prefetched tiles beyond t+1
        if (rem >= 2)      asm volatile("s_waitcnt vmcnt(8)" ::: "memory");
        else if (rem == 1) asm volatile("s_waitcnt vmcnt(4)" ::: "memory");
        else if (rem == 0) asm volatile("s_waitcnt vmcnt(0)" ::: "memory");
        __builtin_amdgcn_s_barrier();
    }
#undef ISSUE

    // ---- epilogue: y = clip(rint(acc * scale), -128, 127) as float
    // 32x32 C/D layout: col = lane&31, row = (reg&3) + 8*(reg>>2) + 4*(lane>>5)
    const float s     = scale_ptr[0];
    const float scale = (s * 0.1f) / 0.1f;   // match ref op order

#pragma unroll
    for (int mi = 0; mi < 4; ++mi) {
#pragma unroll
        for (int nj = 0; nj < 2; ++nj) {
#pragma unroll
            for (int r = 0; r < 16; ++r) {
                int row = bm + wm + mi * 32 + (r & 3) + 8 * (r >> 2) + 4 * fh;
                int col = bn + wn + nj * 32 + fm;
                float y = (float)acc[mi][nj][r] * scale;
                y = rintf(y);
                y = fminf(fmaxf(y, -128.0f), 127.0f);
                out[(size_t)row * N_OUT + col] = y;
            }
        }
    }

    if (bm == 0 && bn == 0 && tid == 0)
        out[(size_t)M_TOK * N_OUT] = 0.1f;
}

// -------------------------------------------------------------------------
extern "C" void kernel_launch(void* const* d_in, const int* in_sizes, int n_in,
                              void* d_out, int out_size, void* d_ws, size_t ws_size,
                              hipStream_t stream)
{
    const int*   x_q     = (const int*)d_in[0];   // [8192*4096] int32 carriers
    const int*   w_q     = (const int*)d_in[1];   // [4096*4096] int32 carriers
    const float* scale_x = (const float*)d_in[2]; // 1 element
    float* out = (float*)d_out;

    char* A8 = (char*)d_ws;                              // 32 MB
    char* B8 = (char*)d_ws + (size_t)M_TOK * K_IN;       // 16 MB

    const int n4x = (M_TOK * K_IN) / 4;   // 8388608
    const int n4w = (N_OUT * K_IN) / 4;   // 4194304

    // one-time: allow 128 KiB dynamic LDS (host-side attribute, not a
    // stream op -> graph-capture safe)
    static bool once = []{
        hipFuncSetAttribute(reinterpret_cast<const void*>(gemm_i8_kernel),
                            hipFuncAttributeMaxDynamicSharedMemorySize,
                            LDS_BYTES);
        return true;
    }();
    (void)once;

    pack_both<<<(n4x + n4w) / 256, 256, 0, stream>>>(
        (const int4*)x_q, (const int4*)w_q, (int*)A8, (int*)B8, n4x, n4w);

    // 512 blocks (16 N-tiles x 32 M-tiles), 512 threads, 128 KiB LDS
    gemm_i8_kernel<<<512, 512, LDS_BYTES, stream>>>(A8, B8, scale_x, out);
}

// Round 2
// 407.483 us; speedup vs baseline: 1.0066x; 1.0066x over previous
//
#include <hip/hip_runtime.h>
#include <stdint.h>

typedef int v4i  __attribute__((ext_vector_type(4)));
typedef int v16i __attribute__((ext_vector_type(16)));

#define M_TOK 8192
#define N_OUT 4096
#define K_IN  4096

#define BM 256
#define BN 256
#define BK 64                      // bytes (= i8 elems) per K-tile
#define NT (K_IN / BK)             // 64 K-tiles
#define RING_STRIDE 32768          // A 16 KiB + B 16 KiB per ring slot
#define LDS_BYTES (4 * RING_STRIDE)  // 128 KiB, ring of 4 (depth-2 prefetch)

// -------------------------------------------------------------------------
// Pack both int32-carrier tensors into int8 in one dispatch. (~38 us,
// BW-bound: 240 MB @ ~6.3 TB/s)
// -------------------------------------------------------------------------
__device__ __forceinline__ int pack4(int4 a) {
    return (a.x & 255) | ((a.y & 255) << 8) | ((a.z & 255) << 16) | ((a.w & 255) << 24);
}

__global__ __launch_bounds__(256) void pack_both(
    const int4* __restrict__ x, const int4* __restrict__ w,
    int* __restrict__ dA, int* __restrict__ dB, int n4x, int n4w)
{
    int i = blockIdx.x * blockDim.x + threadIdx.x;
    if (i < n4x) {
        dA[i] = pack4(x[i]);
    } else {
        int j = i - n4x;
        if (j < n4w) dB[j] = pack4(w[j]);
    }
}

// -------------------------------------------------------------------------
// i8 GEMM, 8-phase-class schedule (T2+T3+T4+T5 port of the 256^2 template):
//   256x256 tile, BK=64, 8 waves (2Mx4N), wave = 128x64 as 4x2 of
//   mfma_i32_32x32x32_i8 (128 acc VGPRs).
//   Ring-4 LDS (128 KiB dynamic), global_load_lds staging, counted
//   s_waitcnt vmcnt(8) once per K-tile (drain 8->4->0 in tail), raw
//   s_barrier pairs per phase, s_setprio(1) around MFMA clusters.
//
// LDS swizzle (R2 fix): rows are 64 B (= half the 128-B bank space); granule
// index is 2 bits (4 x 16 B). R1 used f(r)=(r&3)^((r>>2)&1): conflict-free
// for consecutive-8 lane groups but 4-way for stride-8 groups -> measured
// SQ_LDS_BANK_CONFLICT / ds_read_b128 = 4.0 exactly, MfmaUtil 36.9%.
// New f(r) = ((r>>1)&3) ^ ((r>>3)&3):
//   - consecutive-8 rows: (r1,r2) varies per parity class -> 8 distinct
//     bank-slots (slot = ((r&1)<<2) | granule)
//   - stride-8 rows: (r3,r4) varies -> 4 distinct granules, each slot
//     used exactly 2x across fh halves -> 2-way (free per m136)
// Applied to the GLOBAL source (gload_lds dest is linear lane*16) and to
// the ds_read granule -> same involution both sides (rule #21).
// -------------------------------------------------------------------------
__global__ __launch_bounds__(512, 2) void gemm_i8_kernel(
    const char* __restrict__ A8,      // [M][K] int8 row-major
    const char* __restrict__ B8,      // [N][K] int8 row-major
    const float* __restrict__ scale_ptr,
    float* __restrict__ out)          // [M][N] float + 1 scalar at end
{
    extern __shared__ char lds[];     // 4 ring slots: [A 16K | B 16K] each

    const int tid  = threadIdx.x;
    const int wave = tid >> 6;        // 0..7
    const int lane = tid & 63;

    // ---- bijective XCD swizzle of the 512-block grid (512 % 8 == 0).
    int wg = (blockIdx.x & 7) * 64 + (blockIdx.x >> 3);
    const int bx = wg >> 5;           // 0..15 (N tiles)
    const int by = wg & 31;           // 0..31 (M tiles)
    const int bm = by * BM;
    const int bn = bx * BN;

    const int wr = wave >> 2;         // 0..1
    const int wc = wave & 3;          // 0..3
    const int wm = wr * 128;          // wave row offset in tile
    const int wn = wc * 64;           // wave col offset in tile

    v16i acc[4][2];
#pragma unroll
    for (int mi = 0; mi < 4; ++mi)
#pragma unroll
        for (int nj = 0; nj < 2; ++nj)
#pragma unroll
            for (int r = 0; r < 16; ++r)
                acc[mi][nj][r] = 0;

    // ---- staging geometry: wave-load = 64 lanes x 16 B = 16 rows of 64 B.
    // Wave stages rows [wave*32, wave*32+32) of A and of B (2 loads each).
    // row = r0 + srow, r0 = wave*32 + q*16 (multiple of 16), so
    // f(row) = ((srow>>1)&3) ^ ((srow>>3)&1) ^ (q<<1)  (bits 1-4 of row).
    const int srow = lane >> 2;                                   // 0..15

    const char* gA[2]; const char* gB[2];
    int ldsAoff[2], ldsBoff[2];
#pragma unroll
    for (int q = 0; q < 2; ++q) {
        const int r0  = wave * 32 + q * 16;
        const int f   = ((srow >> 1) & 3) ^ ((srow >> 3) & 1) ^ (q << 1);
        const int sgr = (lane & 3) ^ f;                // swizzled src granule
        gA[q] = A8 + (size_t)(bm + r0 + srow) * K_IN + sgr * 16;
        gB[q] = B8 + (size_t)(bn + r0 + srow) * K_IN + sgr * 16;
        ldsAoff[q] = r0 * 64;              // A at slot offset 0
        ldsBoff[q] = 16384 + r0 * 64;      // B at slot offset 16 KiB
    }

#define ISSUE(tile, q) do {                                                  \
        char* _rb = lds + ((tile) & 3) * RING_STRIDE;                        \
        const int _k0 = (tile) * BK;                                         \
        __builtin_amdgcn_global_load_lds(                                    \
            (const __attribute__((address_space(1))) void*)(gA[q] + _k0),    \
            (__attribute__((address_space(3))) void*)(_rb + ldsAoff[q]),     \
            16, 0, 0);                                                       \
        __builtin_amdgcn_global_load_lds(                                    \
            (const __attribute__((address_space(1))) void*)(gB[q] + _k0),    \
            (__attribute__((address_space(3))) void*)(_rb + ldsBoff[q]),     \
            16, 0, 0);                                                       \
    } while (0)

    // ---- fragment geometry (32x32x32 i8): lane reads 16 B of row fm at
    // global granule g = kk*2 + fh; stored LDS granule = g ^ f(row).
    // row = fm + multiple of 32, so f(row) = ((fm>>1)&3) ^ ((fm>>3)&3).
    const int fm  = lane & 31;
    const int fh  = lane >> 5;                          // 0/1
    const int fsw = ((fm >> 1) & 3) ^ ((fm >> 3) & 3);  // f(row)
    const int g0  = ((0 + fh) ^ fsw) << 4;              // kk=0 byte offset
    const int g1  = ((2 + fh) ^ fsw) << 4;              // kk=1 byte offset
    const int abase = (wm + fm) * 64;                   // + mi*2048
    const int bbase = 16384 + (wn + fm) * 64;           // + nj*2048

    // ---- prologue: tiles 0,1,2 in flight (12 issues/wave)
    ISSUE(0, 0); ISSUE(0, 1);
    ISSUE(1, 0); ISSUE(1, 1);
    ISSUE(2, 0); ISSUE(2, 1);
    asm volatile("s_waitcnt vmcnt(8)" ::: "memory");   // tile 0 landed
    __builtin_amdgcn_s_barrier();

    for (int t = 0; t < NT; ++t) {
        char* rb = lds + (t & 3) * RING_STRIDE;
        const bool pf = (t + 3 < NT);
        v4i af[4], bf[2];

        // ================= phase 0 (kk = 0) =================
#pragma unroll
        for (int mi = 0; mi < 4; ++mi)
            af[mi] = *(const v4i*)(rb + abase + mi * 2048 + g0);
#pragma unroll
        for (int nj = 0; nj < 2; ++nj)
            bf[nj] = *(const v4i*)(rb + bbase + nj * 2048 + g0);
        if (pf) ISSUE(t + 3, 0);           // 2 prefetch issues
        __builtin_amdgcn_s_barrier();
        __builtin_amdgcn_s_setprio(1);
#pragma unroll
        for (int mi = 0; mi < 4; ++mi)
#pragma unroll
            for (int nj = 0; nj < 2; ++nj)
                acc[mi][nj] = __builtin_amdgcn_mfma_i32_32x32x32_i8(
                    af[mi], bf[nj], acc[mi][nj], 0, 0, 0);
        __builtin_amdgcn_s_setprio(0);
        __builtin_amdgcn_s_barrier();

        // ================= phase 1 (kk = 1) =================
#pragma unroll
        for (int mi = 0; mi < 4; ++mi)
            af[mi] = *(const v4i*)(rb + abase + mi * 2048 + g1);
#pragma unroll
        for (int nj = 0; nj < 2; ++nj)
            bf[nj] = *(const v4i*)(rb + bbase + nj * 2048 + g1);
        if (pf) ISSUE(t + 3, 1);           // remaining 2 prefetch issues
        __builtin_amdgcn_s_barrier();
        __builtin_amdgcn_s_setprio(1);
#pragma unroll
        for (int mi = 0; mi < 4; ++mi)
#pragma unroll
            for (int nj = 0; nj < 2; ++nj)
                acc[mi][nj] = __builtin_amdgcn_mfma_i32_32x32x32_i8(
                    af[mi], bf[nj], acc[mi][nj], 0, 0, 0);
        __builtin_amdgcn_s_setprio(0);

        // counted wait: tile t+1 must be resident before next iteration's
        // ds_reads. Newest 8 vmem ops = tiles t+2, t+3; everything older
        // (t+1) must have landed.
        const int rem = NT - 2 - t;        // prefetched tiles beyond t+1
        if (rem >= 2)      asm volatile("s_waitcnt vmcnt(8)" ::: "memory");
        else if (rem == 1) asm volatile("s_waitcnt vmcnt(4)" ::: "memory");
        else if (rem == 0) asm volatile("s_waitcnt vmcnt(0)" ::: "memory");
        __builtin_amdgcn_s_barrier();
    }
#undef ISSUE

    // ---- epilogue: y = clip(rint(acc * scale), -128, 127) as float
    // 32x32 C/D layout: col = lane&31, row = (reg&3) + 8*(reg>>2) + 4*(lane>>5)
    const float s     = scale_ptr[0];
    const float scale = (s * 0.1f) / 0.1f;   // match ref op order

#pragma unroll
    for (int mi = 0; mi < 4; ++mi) {
#pragma unroll
        for (int nj = 0; nj < 2; ++nj) {
#pragma unroll
            for (int r = 0; r < 16; ++r) {
                int row = bm + wm + mi * 32 + (r & 3) + 8 * (r >> 2) + 4 * fh;
                int col = bn + wn + nj * 32 + fm;
                float y = (float)acc[mi][nj][r] * scale;
                y = rintf(y);
                y = fminf(fmaxf(y, -128.0f), 127.0f);
                out[(size_t)row * N_OUT + col] = y;
            }
        }
    }

    if (bm == 0 && bn == 0 && tid == 0)
        out[(size_t)M_TOK * N_OUT] = 0.1f;
}

// -------------------------------------------------------------------------
extern "C" void kernel_launch(void* const* d_in, const int* in_sizes, int n_in,
                              void* d_out, int out_size, void* d_ws, size_t ws_size,
                              hipStream_t stream)
{
    const int*   x_q     = (const int*)d_in[0];   // [8192*4096] int32 carriers
    const int*   w_q     = (const int*)d_in[1];   // [4096*4096] int32 carriers
    const float* scale_x = (const float*)d_in[2]; // 1 element
    float* out = (float*)d_out;

    char* A8 = (char*)d_ws;                              // 32 MB
    char* B8 = (char*)d_ws + (size_t)M_TOK * K_IN;       // 16 MB

    const int n4x = (M_TOK * K_IN) / 4;   // 8388608
    const int n4w = (N_OUT * K_IN) / 4;   // 4194304

    // one-time: allow 128 KiB dynamic LDS (host-side attribute, not a
    // stream op -> graph-capture safe)
    static bool once = []{
        hipFuncSetAttribute(reinterpret_cast<const void*>(gemm_i8_kernel),
                            hipFuncAttributeMaxDynamicSharedMemorySize,
                            LDS_BYTES);
        return true;
    }();
    (void)once;

    pack_both<<<(n4x + n4w) / 256, 256, 0, stream>>>(
        (const int4*)x_q, (const int4*)w_q, (int*)A8, (int*)B8, n4x, n4w);

    // 512 blocks (16 N-tiles x 32 M-tiles), 512 threads, 128 KiB LDS
    gemm_i8_kernel<<<512, 512, LDS_BYTES, stream>>>(A8, B8, scale_x, out);
}

// Round 3
// 394.451 us; speedup vs baseline: 1.0398x; 1.0330x over previous
//
#include <hip/hip_runtime.h>
#include <stdint.h>

typedef int v4i  __attribute__((ext_vector_type(4)));
typedef int v16i __attribute__((ext_vector_type(16)));

#define M_TOK 8192
#define N_OUT 4096
#define K_IN  4096

#define BM 256
#define BN 256
#define BK 64                      // bytes (= i8 elems) per K-tile
#define NT (K_IN / BK)             // 64 K-tiles
#define RING_STRIDE 32768          // A 16 KiB + B 16 KiB per ring slot
#define LDS_BYTES (4 * RING_STRIDE)  // 128 KiB, ring of 4 (depth-2 prefetch)

// -------------------------------------------------------------------------
// Pack both int32-carrier tensors into int8 in one dispatch. (~38 us,
// BW-bound: 240 MB @ ~6.3 TB/s)
// -------------------------------------------------------------------------
__device__ __forceinline__ int pack4(int4 a) {
    return (a.x & 255) | ((a.y & 255) << 8) | ((a.z & 255) << 16) | ((a.w & 255) << 24);
}

__global__ __launch_bounds__(256) void pack_both(
    const int4* __restrict__ x, const int4* __restrict__ w,
    int* __restrict__ dA, int* __restrict__ dB, int n4x, int n4w)
{
    int i = blockIdx.x * blockDim.x + threadIdx.x;
    if (i < n4x) {
        dA[i] = pack4(x[i]);
    } else {
        int j = i - n4x;
        if (j < n4w) dB[j] = pack4(w[j]);
    }
}

// -------------------------------------------------------------------------
// i8 GEMM, 256x256 tile, BK=64, 8 waves (2Mx4N), wave = 128x64 as 4x2 of
// mfma_i32_32x32x32_i8. Ring-4 LDS (128 KiB), global_load_lds staging,
// counted s_waitcnt vmcnt(8) once per K-tile.
//
// R3 structure change: ONE barrier per K-tile (was 4). R2 counters showed
// SQ_LDS_BANK_CONFLICT = 12.0 per gload_lds write, bit-identical across
// two different read swizzles -> the counter is the gload write-burst
// fixed cost; reads are conflict-free. Measured 3075 cyc/tile vs MFMA
// 1170 + LDS ~1140: both pipes <50% busy -> the loss is barrier-lockstep
// (read-burst | MFMA-burst alternation + skew drain at 4 barriers/tile).
// Mid-tile barriers are scheduling-only: each wave's tile-t reads drain
// via its own MFMA lgkm deps before the tile-end barrier, and slot t+3
// (== slot t-1) is only written by gloads issued after that barrier.
// Free-running waves inside a tile restore m114-style pipe overlap
// (2 waves/SIMD at different program points); setprio(1) around MFMA
// clusters now has role-diversity to arbitrate (T5 regime).
// AITER hand-asm reference: ~32 MFMA/barrier; this gives 16/barrier (was 8
// per 2 barriers).
// -------------------------------------------------------------------------
__global__ __launch_bounds__(512, 2) void gemm_i8_kernel(
    const char* __restrict__ A8,      // [M][K] int8 row-major
    const char* __restrict__ B8,      // [N][K] int8 row-major
    const float* __restrict__ scale_ptr,
    float* __restrict__ out)          // [M][N] float + 1 scalar at end
{
    extern __shared__ char lds[];     // 4 ring slots: [A 16K | B 16K] each

    const int tid  = threadIdx.x;
    const int wave = tid >> 6;        // 0..7
    const int lane = tid & 63;

    // ---- bijective XCD swizzle of the 512-block grid (512 % 8 == 0).
    int wg = (blockIdx.x & 7) * 64 + (blockIdx.x >> 3);
    const int bx = wg >> 5;           // 0..15 (N tiles)
    const int by = wg & 31;           // 0..31 (M tiles)
    const int bm = by * BM;
    const int bn = bx * BN;

    const int wr = wave >> 2;         // 0..1
    const int wc = wave & 3;          // 0..3
    const int wm = wr * 128;          // wave row offset in tile
    const int wn = wc * 64;           // wave col offset in tile

    v16i acc[4][2];
#pragma unroll
    for (int mi = 0; mi < 4; ++mi)
#pragma unroll
        for (int nj = 0; nj < 2; ++nj)
#pragma unroll
            for (int r = 0; r < 16; ++r)
                acc[mi][nj][r] = 0;

    // ---- staging geometry: wave-load = 64 lanes x 16 B = 16 rows of 64 B.
    // Wave stages rows [wave*32, wave*32+32) of A and of B (2 loads each).
    // Source granule pre-swizzled (gload_lds dest is linear lane*16):
    // f(row) = ((row>>1)&3) ^ ((row>>3)&3), row = r0 + srow.
    const int srow = lane >> 2;                                   // 0..15

    const char* gA[2]; const char* gB[2];
    int ldsAoff[2], ldsBoff[2];
#pragma unroll
    for (int q = 0; q < 2; ++q) {
        const int r0  = wave * 32 + q * 16;
        const int f   = ((srow >> 1) & 3) ^ ((srow >> 3) & 1) ^ (q << 1);
        const int sgr = (lane & 3) ^ f;                // swizzled src granule
        gA[q] = A8 + (size_t)(bm + r0 + srow) * K_IN + sgr * 16;
        gB[q] = B8 + (size_t)(bn + r0 + srow) * K_IN + sgr * 16;
        ldsAoff[q] = r0 * 64;              // A at slot offset 0
        ldsBoff[q] = 16384 + r0 * 64;      // B at slot offset 16 KiB
    }

#define ISSUE(tile, q) do {                                                  \
        char* _rb = lds + ((tile) & 3) * RING_STRIDE;                        \
        const int _k0 = (tile) * BK;                                         \
        __builtin_amdgcn_global_load_lds(                                    \
            (const __attribute__((address_space(1))) void*)(gA[q] + _k0),    \
            (__attribute__((address_space(3))) void*)(_rb + ldsAoff[q]),     \
            16, 0, 0);                                                       \
        __builtin_amdgcn_global_load_lds(                                    \
            (const __attribute__((address_space(1))) void*)(gB[q] + _k0),    \
            (__attribute__((address_space(3))) void*)(_rb + ldsBoff[q]),     \
            16, 0, 0);                                                       \
    } while (0)

    // ---- fragment geometry (32x32x32 i8): lane reads 16 B of row fm at
    // global granule g = kk*2 + fh; stored LDS granule = g ^ f(row).
    const int fm  = lane & 31;
    const int fh  = lane >> 5;                          // 0/1
    const int fsw = ((fm >> 1) & 3) ^ ((fm >> 3) & 3);  // f(row)
    const int g0  = ((0 + fh) ^ fsw) << 4;              // kk=0 byte offset
    const int g1  = ((2 + fh) ^ fsw) << 4;              // kk=1 byte offset
    const int abase = (wm + fm) * 64;                   // + mi*2048
    const int bbase = 16384 + (wn + fm) * 64;           // + nj*2048

    // ---- prologue: tiles 0,1,2 in flight (12 issues/wave)
    ISSUE(0, 0); ISSUE(0, 1);
    ISSUE(1, 0); ISSUE(1, 1);
    ISSUE(2, 0); ISSUE(2, 1);
    asm volatile("s_waitcnt vmcnt(8)" ::: "memory");   // tile 0 landed
    __builtin_amdgcn_s_barrier();

    for (int t = 0; t < NT; ++t) {
        char* rb = lds + (t & 3) * RING_STRIDE;
        const bool pf = (t + 3 < NT);
        v4i af[4], bf[2];

        // ---- kk = 0: reads + prefetch issue + MFMA (no barrier)
#pragma unroll
        for (int mi = 0; mi < 4; ++mi)
            af[mi] = *(const v4i*)(rb + abase + mi * 2048 + g0);
#pragma unroll
        for (int nj = 0; nj < 2; ++nj)
            bf[nj] = *(const v4i*)(rb + bbase + nj * 2048 + g0);
        if (pf) ISSUE(t + 3, 0);
        __builtin_amdgcn_s_setprio(1);
#pragma unroll
        for (int mi = 0; mi < 4; ++mi)
#pragma unroll
            for (int nj = 0; nj < 2; ++nj)
                acc[mi][nj] = __builtin_amdgcn_mfma_i32_32x32x32_i8(
                    af[mi], bf[nj], acc[mi][nj], 0, 0, 0);
        __builtin_amdgcn_s_setprio(0);

        // ---- kk = 1: reads + prefetch issue + MFMA (no barrier)
        v4i af1[4], bf1[2];
#pragma unroll
        for (int mi = 0; mi < 4; ++mi)
            af1[mi] = *(const v4i*)(rb + abase + mi * 2048 + g1);
#pragma unroll
        for (int nj = 0; nj < 2; ++nj)
            bf1[nj] = *(const v4i*)(rb + bbase + nj * 2048 + g1);
        if (pf) ISSUE(t + 3, 1);
        __builtin_amdgcn_s_setprio(1);
#pragma unroll
        for (int mi = 0; mi < 4; ++mi)
#pragma unroll
            for (int nj = 0; nj < 2; ++nj)
                acc[mi][nj] = __builtin_amdgcn_mfma_i32_32x32x32_i8(
                    af1[mi], bf1[nj], acc[mi][nj], 0, 0, 0);
        __builtin_amdgcn_s_setprio(0);

        // ---- tile boundary: counted wait (never 0 mid-loop) + ONE barrier.
        // After every wave passes: all waves' tile-t reads are drained (MFMA
        // lgkm deps) and all waves' t+1 gloads have landed (own vmcnt).
        const int rem = NT - 2 - t;        // prefetched tiles beyond t+1
        if (rem >= 2)      asm volatile("s_waitcnt vmcnt(8)" ::: "memory");
        else if (rem == 1) asm volatile("s_waitcnt vmcnt(4)" ::: "memory");
        else if (rem == 0) asm volatile("s_waitcnt vmcnt(0)" ::: "memory");
        __builtin_amdgcn_s_barrier();
    }
#undef ISSUE

    // ---- epilogue: y = clip(rint(acc * scale), -128, 127) as float
    // 32x32 C/D layout: col = lane&31, row = (reg&3) + 8*(reg>>2) + 4*(lane>>5)
    const float s     = scale_ptr[0];
    const float scale = (s * 0.1f) / 0.1f;   // match ref op order

#pragma unroll
    for (int mi = 0; mi < 4; ++mi) {
#pragma unroll
        for (int nj = 0; nj < 2; ++nj) {
#pragma unroll
            for (int r = 0; r < 16; ++r) {
                int row = bm + wm + mi * 32 + (r & 3) + 8 * (r >> 2) + 4 * fh;
                int col = bn + wn + nj * 32 + fm;
                float y = (float)acc[mi][nj][r] * scale;
                y = rintf(y);
                y = fminf(fmaxf(y, -128.0f), 127.0f);
                out[(size_t)row * N_OUT + col] = y;
            }
        }
    }

    if (bm == 0 && bn == 0 && tid == 0)
        out[(size_t)M_TOK * N_OUT] = 0.1f;
}

// -------------------------------------------------------------------------
extern "C" void kernel_launch(void* const* d_in, const int* in_sizes, int n_in,
                              void* d_out, int out_size, void* d_ws, size_t ws_size,
                              hipStream_t stream)
{
    const int*   x_q     = (const int*)d_in[0];   // [8192*4096] int32 carriers
    const int*   w_q     = (const int*)d_in[1];   // [4096*4096] int32 carriers
    const float* scale_x = (const float*)d_in[2]; // 1 element
    float* out = (float*)d_out;

    char* A8 = (char*)d_ws;                              // 32 MB
    char* B8 = (char*)d_ws + (size_t)M_TOK * K_IN;       // 16 MB

    const int n4x = (M_TOK * K_IN) / 4;   // 8388608
    const int n4w = (N_OUT * K_IN) / 4;   // 4194304

    // one-time: allow 128 KiB dynamic LDS (host-side attribute, not a
    // stream op -> graph-capture safe)
    static bool once = []{
        hipFuncSetAttribute(reinterpret_cast<const void*>(gemm_i8_kernel),
                            hipFuncAttributeMaxDynamicSharedMemorySize,
                            LDS_BYTES);
        return true;
    }();
    (void)once;

    pack_both<<<(n4x + n4w) / 256, 256, 0, stream>>>(
        (const int4*)x_q, (const int4*)w_q, (int*)A8, (int*)B8, n4x, n4w);

    // 512 blocks (16 N-tiles x 32 M-tiles), 512 threads, 128 KiB LDS
    gemm_i8_kernel<<<512, 512, LDS_BYTES, stream>>>(A8, B8, scale_x, out);
}